// Round 11
// baseline (175.429 us; speedup 1.0000x reference)
//
#include <hip/hip_runtime.h>
#include <hip/hip_bf16.h>

#define Bdim 512
#define Sdim 50
#define Hdim 512
#define Ndim 20000
#define Kdim2 1024   // 2*H
#define SEENW 640    // u32 words per row for the seen-bitmask (20000 bits -> 625, pad 640)

typedef __bf16 bf16x8 __attribute__((ext_vector_type(8)));
typedef float f32x4 __attribute__((ext_vector_type(4)));
typedef unsigned short u16;

#define AS1 __attribute__((address_space(1)))
#define AS3 __attribute__((address_space(3)))

__device__ __forceinline__ u16 f2bf(float f) {
  unsigned u = __builtin_bit_cast(unsigned, f);
  u = (u + 0x7fffu + ((u >> 16) & 1u)) >> 16;   // RNE
  return (u16)u;
}
// HW packed fp32->bf16 (RNE), lo -> [15:0], hi -> [31:16]
__device__ __forceinline__ unsigned cvt_pk_bf16(float lo, float hi) {
  unsigned r;
  asm("v_cvt_pk_bf16_f32 %0, %1, %2" : "=v"(r) : "v"(lo), "v"(hi));
  return r;
}
__device__ __forceinline__ bf16x8 pack8(float4 lo, float4 hi) {
  union { unsigned u[4]; bf16x8 v; } r;
  r.u[0] = cvt_pk_bf16(lo.x, lo.y);
  r.u[1] = cvt_pk_bf16(lo.z, lo.w);
  r.u[2] = cvt_pk_bf16(hi.x, hi.y);
  r.u[3] = cvt_pk_bf16(hi.z, hi.w);
  return r.v;
}

// ---------------- prep: cast last_memory/W_w/U_w + zero scores/lm/seen ----------
__global__ __launch_bounds__(256) void prep_kernel(const float* __restrict__ a, u16* __restrict__ da,
                                                   const float* __restrict__ b, u16* __restrict__ db,
                                                   const float* __restrict__ c, u16* __restrict__ dc,
                                                   float* __restrict__ scores, float* __restrict__ lm,
                                                   unsigned* __restrict__ seen) {
  int i = blockIdx.x * blockDim.x + threadIdx.x;   // 65536 threads, one float4 each
  float4 v; ushort4 o;
  v = reinterpret_cast<const float4*>(a)[i];
  o.x = f2bf(v.x); o.y = f2bf(v.y); o.z = f2bf(v.z); o.w = f2bf(v.w);
  reinterpret_cast<ushort4*>(da)[i] = o;
  v = reinterpret_cast<const float4*>(b)[i];
  o.x = f2bf(v.x); o.y = f2bf(v.y); o.z = f2bf(v.z); o.w = f2bf(v.w);
  reinterpret_cast<ushort4*>(db)[i] = o;
  v = reinterpret_cast<const float4*>(c)[i];
  o.x = f2bf(v.x); o.y = f2bf(v.y); o.z = f2bf(v.z); o.w = f2bf(v.w);
  reinterpret_cast<ushort4*>(dc)[i] = o;
  int stride = gridDim.x * blockDim.x;
  for (int j = i; j < Bdim * Sdim; j += stride) scores[j] = 0.f;
  for (int j = i; j < Bdim * Hdim; j += stride) lm[j] = 0.f;
  for (int j = i; j < Bdim * SEENW; j += stride) seen[j] = 0u;
}

// ---------------- seen-item scatter ----------------
__global__ __launch_bounds__(256) void scatter_kernel(const int* __restrict__ iseq,
                                                      unsigned* __restrict__ seen) {
  int i = blockIdx.x * blockDim.x + threadIdx.x;
  if (i < Bdim * Sdim) {
    int b = i / Sdim;
    int it = iseq[i];
    if (it > 0) atomicOr(&seen[b * SEENW + (it >> 5)], 1u << (it & 31));
  }
}

// ---------------- softmax over S + context readout -> feat (bf16) ----------------
__global__ __launch_bounds__(256) void softmax_ctx_kernel(
    const float* __restrict__ scores, const unsigned char* __restrict__ mask,
    const float* __restrict__ amF, const float* __restrict__ last_memory,
    u16* __restrict__ feat) {
  int b = blockIdx.x;
  __shared__ float alpha[Sdim];
  int tid = threadIdx.x;
  if (tid < 64) {
    float s = -1e30f;
    if (tid < Sdim) {
      s = scores[b * Sdim + tid];
      if (mask[b * Sdim + tid]) s = -1e9f;   // mask is all-false in this problem
    }
    float m = s;
#pragma unroll
    for (int off = 32; off; off >>= 1) m = fmaxf(m, __shfl_xor(m, off));
    float e = (tid < Sdim) ? __expf(s - m) : 0.f;
    float sum = e;
#pragma unroll
    for (int off = 32; off; off >>= 1) sum += __shfl_xor(sum, off);
    if (tid < Sdim) alpha[tid] = e / sum;
  }
  __syncthreads();
  for (int h = tid; h < Hdim; h += 256) {
    const float* amp = amF + ((long)b * Sdim) * Hdim + h;
    float c = 0.f;
#pragma unroll 5
    for (int s = 0; s < Sdim; ++s) c += alpha[s] * amp[(long)s * Hdim];
    feat[b * Kdim2 + h] = f2bf(c);
    feat[b * Kdim2 + Hdim + h] = f2bf(last_memory[b * Hdim + h]);
  }
}

// ---------------- gemm_bt: 2-phase schedule for lm GEMM (EPI0) + scores GEMM (EPI1)
#define BM 256
#define BN 128
#define BK 32

template <int EPI>
__global__ __launch_bounds__(512, 4) void gemm_bt(
    const u16* __restrict__ A, const u16* __restrict__ Bmat,
    const float* __restrict__ Af,
    int M, int N, int K,
    float* __restrict__ out,
    const float* __restrict__ lm, const float* __restrict__ Vw,
    float* __restrict__ scores) {
  __shared__ bf16x8 Asl[2][BM * BK / 8];   // 2 x 1024 chunks of 16B = 32 KB
  __shared__ bf16x8 Bsl[2][BN * BK / 8];   // 2 x  512 chunks of 16B = 16 KB
  const int tid = threadIdx.x;
  const int lane = tid & 63;
  const int wid = tid >> 6;                 // 0..7
  const int wr = wid >> 1, wc = wid & 1;    // 4x2 wave grid, 64x64 per wave
  const int la = lane & 15, lb = lane >> 4;

  int bx, by, kt0, kt1;
  if constexpr (EPI == 0) {
    bx = blockIdx.x; by = blockIdx.y;
    int ktotal = K / BK; int kper = ktotal / gridDim.z;
    kt0 = blockIdx.z * kper; kt1 = kt0 + kper;
  } else {
    int nwg = gridDim.x, bid = blockIdx.x;
    int q = nwg >> 3, r = nwg & 7;
    int x = bid & 7, i = bid >> 3;
    int wgid = (x < r ? x * (q + 1) : r * (q + 1) + (x - r) * q) + i;
    by = wgid >> 2; bx = wgid & 3;          // 4 n-tiles of one A m-panel per XCD
    kt0 = 0; kt1 = K / BK;
  }
  const int m0 = by * BM;
  const int n0 = bx * BN;

  f32x4 acc[4][4];
  const f32x4 zero = {0.f, 0.f, 0.f, 0.f};
#pragma unroll
  for (int i = 0; i < 4; ++i)
#pragma unroll
    for (int j = 0; j < 4; ++j) acc[i][j] = zero;

  const int rw = tid >> 2;
  const int eA = (tid & 3) * 8;
  const int ch = tid & 3;
  int brB = n0 + rw; if (brB > N - 1) brB = N - 1;

  const u16 *gA0 = nullptr, *gA1 = nullptr, *gB = nullptr;
  const float *gAf0 = nullptr, *gAf1 = nullptr;
  if constexpr (EPI == 1) {
    gAf0 = Af + (long)(m0 + rw) * K + eA;
    gAf1 = Af + (long)(m0 + 128 + rw) * K + eA;
  } else {
    gA0 = A + (long)(m0 + rw) * K + eA;
    gA1 = A + (long)(m0 + 128 + rw) * K + eA;
  }
  gB = Bmat + (long)brB * K + eA;

  float4 ra0, ra1, ra2, ra3;   // EPI1: A fp32 staging regs

  auto STAGE_G = [&](int buf, int kt) {
    const int k0 = kt * BK;
    if constexpr (EPI != 1) {
      __builtin_amdgcn_global_load_lds((const AS1 void*)(gA0 + k0),
                                       (AS3 void*)(void*)&Asl[buf][wid * 64], 16, 0, 0);
      __builtin_amdgcn_global_load_lds((const AS1 void*)(gA1 + k0),
                                       (AS3 void*)(void*)&Asl[buf][512 + wid * 64], 16, 0, 0);
    }
    __builtin_amdgcn_global_load_lds((const AS1 void*)(gB + k0),
                                     (AS3 void*)(void*)&Bsl[buf][wid * 64], 16, 0, 0);
  };
  auto LOADR = [&](int kt) {
    const int k0 = kt * BK;
    if constexpr (EPI == 1) {
      ra0 = *reinterpret_cast<const float4*>(gAf0 + k0);
      ra1 = *reinterpret_cast<const float4*>(gAf0 + k0 + 4);
      ra2 = *reinterpret_cast<const float4*>(gAf1 + k0);
      ra3 = *reinterpret_cast<const float4*>(gAf1 + k0 + 4);
    }
  };
  auto WRITER = [&](int buf) {
    if constexpr (EPI == 1) {
      Asl[buf][rw * 4 + ch] = pack8(ra0, ra1);
      Asl[buf][(128 + rw) * 4 + ch] = pack8(ra2, ra3);
    }
  };

  STAGE_G(0, kt0);
  LOADR(kt0);
  WRITER(0);
  __syncthreads();
  int cur = 0;
  for (int kt = kt0; kt < kt1; ++kt) {
    const bool pf = (kt + 1 < kt1);
    if (pf) { STAGE_G(cur ^ 1, kt + 1); LOADR(kt + 1); }

    bf16x8 af[4], bfr[4];
#pragma unroll
    for (int mi = 0; mi < 4; ++mi)
      af[mi] = Asl[cur][(wr * 64 + mi * 16 + la) * 4 + lb];
#pragma unroll
    for (int ni = 0; ni < 4; ++ni)
      bfr[ni] = Bsl[cur][(wc * 64 + ni * 16 + la) * 4 + lb];
#pragma unroll
    for (int mi = 0; mi < 4; ++mi)
#pragma unroll
      for (int ni = 0; ni < 4; ++ni)
        acc[mi][ni] = __builtin_amdgcn_mfma_f32_16x16x32_bf16(af[mi], bfr[ni], acc[mi][ni], 0, 0, 0);

    if (pf) WRITER(cur ^ 1);
    __syncthreads();
    cur ^= 1;
  }

  // C/D layout (verified): col = lane&15, row = (lane>>4)*4 + reg
  if constexpr (EPI == 0) {
#pragma unroll
    for (int mi = 0; mi < 4; ++mi)
#pragma unroll
      for (int i = 0; i < 4; ++i) {
        int r = m0 + wr * 64 + mi * 16 + lb * 4 + i;
#pragma unroll
        for (int ni = 0; ni < 4; ++ni) {
          int c = n0 + wc * 64 + ni * 16 + la;
          atomicAdd(&out[(long)r * N + c], acc[mi][ni][i]);
        }
      }
  }
  if constexpr (EPI == 1) {
#pragma unroll
    for (int mi = 0; mi < 4; ++mi)
#pragma unroll
      for (int i = 0; i < 4; ++i) {
        int r = m0 + wr * 64 + mi * 16 + lb * 4 + i;
        int bidx = r / Sdim;
        float p = 0.f;
#pragma unroll
        for (int ni = 0; ni < 4; ++ni) {
          int c = n0 + wc * 64 + ni * 16 + la;
          float x = acc[mi][ni][i] + lm[bidx * Hdim + c];
          x = fminf(fmaxf(x, -9.f), 9.f);
          float e = __expf(2.f * x);
          p += Vw[c] * ((e - 1.f) / (e + 1.f));
        }
        p += __shfl_xor(p, 1);
        p += __shfl_xor(p, 2);
        p += __shfl_xor(p, 4);
        p += __shfl_xor(p, 8);
        if (la == 0) atomicAdd(&scores[r], p);
      }
  }
}

// ---------------- gemm_logits v5: TRANSPOSED into EPI1's proven geometry -------
// Compute out^T = E_w . feat^T :
//   A-operand = E_w fp32 [M'=20000 x K=1024]  -> the HBM stream sits on the
//     M side, reg-staged with fused cvt_pk (EPI1's verbatim staging path)
//   B-operand = feat bf16 [N'=512 x K]        -> L2-resident, global_load_lds
// Grid: 79 m-panels x 4 n-tiles = 316 blocks; XCD swizzle groups the 4
// n-tiles of one E-panel per XCD (E_w read ONCE from HBM, 4-way L2-shared —
// exactly EPI1's sharing pattern, the only structure measured at ~1900cyc/iter).
// LDS 48 KB -> 3 blocks/CU. Plain 2-phase __syncthreads loop, no fences.
// Epilogue stores the transposed fragment: out[r=n'][c=m'] with sigmoid +
// seen-mask; blocks fill complete 1KB row-spans so L2 write-combines to 40MB.
// E-rows >= 20000 clamp to 19999 (loaded, computed, never stored).
__global__ __launch_bounds__(512, 4) void gemm_logits(
    const float* __restrict__ Ef, const u16* __restrict__ Feat,
    float* __restrict__ out, const unsigned* __restrict__ seen) {
  __shared__ bf16x8 Asl[2][BM * BK / 8];   // E-tile (bf16 after cvt): 32 KB
  __shared__ bf16x8 Bsl[2][BN * BK / 8];   // feat tile: 16 KB
  const int tid = threadIdx.x;
  const int lane = tid & 63;
  const int wid = tid >> 6;
  const int wr = wid >> 1, wc = wid & 1;    // 4m x 2n waves, 64x64 per wave
  const int la = lane & 15, lb = lane >> 4;
  const int NT = Kdim2 / BK;                // 32

  // bijective XCD swizzle (nwg=316): 4 n-tiles of one E m-panel consecutive
  int nwg = gridDim.x, bid = blockIdx.x;
  int q = nwg >> 3, r = nwg & 7;
  int x = bid & 7, i0 = bid >> 3;
  int wgid = (x < r ? x * (q + 1) : r * (q + 1) + (x - r) * q) + i0;
  const int by = wgid >> 2, bx = wgid & 3;
  const int m0 = by * BM;                   // E-row panel (0..79*256)
  const int n0 = bx * BN;                   // feat-row tile (0..511)

  f32x4 acc[4][4];
  const f32x4 zero = {0.f, 0.f, 0.f, 0.f};
#pragma unroll
  for (int i = 0; i < 4; ++i)
#pragma unroll
    for (int j = 0; j < 4; ++j) acc[i][j] = zero;

  const int rw = tid >> 2;
  const int eA = (tid & 3) * 8;
  const int ch = tid & 3;

  long ar0 = m0 + rw;        if (ar0 > Ndim - 1) ar0 = Ndim - 1;   // clamp E rows
  long ar1 = m0 + 128 + rw;  if (ar1 > Ndim - 1) ar1 = Ndim - 1;
  const float* gAf0 = Ef + ar0 * Kdim2 + eA;
  const float* gAf1 = Ef + ar1 * Kdim2 + eA;
  const u16* gB = Feat + (long)(n0 + rw) * Kdim2 + eA;   // n0+rw <= 511 always

  float4 ra0, ra1, ra2, ra3;

  auto STAGE_G = [&](int buf, int kt) {     // feat -> LDS (async, L2-hot)
    const int k0 = kt * BK;
    __builtin_amdgcn_global_load_lds((const AS1 void*)(gB + k0),
                                     (AS3 void*)(void*)&Bsl[buf][wid * 64], 16, 0, 0);
  };
  auto LOADR = [&](int kt) {                // E_w fp32 stream -> regs
    const int k0 = kt * BK;
    ra0 = *reinterpret_cast<const float4*>(gAf0 + k0);
    ra1 = *reinterpret_cast<const float4*>(gAf0 + k0 + 4);
    ra2 = *reinterpret_cast<const float4*>(gAf1 + k0);
    ra3 = *reinterpret_cast<const float4*>(gAf1 + k0 + 4);
  };
  auto WRITER = [&](int buf) {              // cvt + ds_write after MFMA phase
    Asl[buf][rw * 4 + ch] = pack8(ra0, ra1);
    Asl[buf][(128 + rw) * 4 + ch] = pack8(ra2, ra3);
  };

  STAGE_G(0, 0);
  LOADR(0);
  WRITER(0);
  __syncthreads();
  int cur = 0;
  for (int kt = 0; kt < NT; ++kt) {
    const bool pf = (kt + 1 < NT);
    if (pf) { STAGE_G(cur ^ 1, kt + 1); LOADR(kt + 1); }

    bf16x8 af[4], bfr[4];
#pragma unroll
    for (int mi = 0; mi < 4; ++mi)
      af[mi] = Asl[cur][(wr * 64 + mi * 16 + la) * 4 + lb];
#pragma unroll
    for (int ni = 0; ni < 4; ++ni)
      bfr[ni] = Bsl[cur][(wc * 64 + ni * 16 + la) * 4 + lb];
#pragma unroll
    for (int mi = 0; mi < 4; ++mi)
#pragma unroll
      for (int ni = 0; ni < 4; ++ni)
        acc[mi][ni] = __builtin_amdgcn_mfma_f32_16x16x32_bf16(af[mi], bfr[ni], acc[mi][ni], 0, 0, 0);

    if (pf) WRITER(cur ^ 1);
    __syncthreads();
    cur ^= 1;
  }

  // epilogue: transposed store, sigmoid + seen-mask
  // acc row (lane>>4)*4+reg = m' (E-row -> out COLUMN), col lane&15 = n' (out ROW)
#pragma unroll
  for (int mi = 0; mi < 4; ++mi)
#pragma unroll
    for (int i = 0; i < 4; ++i) {
      int c = m0 + wr * 64 + mi * 16 + lb * 4 + i;   // item index
      if (c < Ndim) {
#pragma unroll
        for (int ni = 0; ni < 4; ++ni) {
          int rr = n0 + wc * 64 + ni * 16 + la;      // batch row
          unsigned wbits = seen[rr * SEENW + (c >> 5)];
          float val = 0.f;
          if (!((wbits >> (c & 31)) & 1u))
            val = 1.f / (1.f + __expf(-acc[mi][ni][i]));
          out[(long)rr * Ndim + c] = val;
        }
      }
    }
}

// ---------------- launcher ----------------
extern "C" void kernel_launch(void* const* d_in, const int* in_sizes, int n_in,
                              void* d_out, int out_size, void* d_ws, size_t ws_size,
                              hipStream_t stream) {
  (void)in_sizes; (void)n_in; (void)out_size; (void)ws_size;
  const float* all_memory  = (const float*)d_in[0];
  const float* last_memory = (const float*)d_in[1];
  const int*   item_seq    = (const int*)d_in[2];
  const unsigned char* mask = (const unsigned char*)d_in[3];
  const float* U_w = (const float*)d_in[4];
  const float* W_w = (const float*)d_in[5];
  const float* V_w = (const float*)d_in[6];
  const float* E_w = (const float*)d_in[8];
  float* out = (float*)d_out;

  char* w = (char*)d_ws;
  u16* wsFeat = (u16*)w; w += (size_t)Bdim * Kdim2 * 2;         // 1 MB
  u16* wsLast = (u16*)w; w += (size_t)Hdim * Hdim * 2;          // 0.5 MB
  u16* wsW    = (u16*)w; w += (size_t)Hdim * Hdim * 2;
  u16* wsU    = (u16*)w; w += (size_t)Hdim * Hdim * 2;
  float* wsLm     = (float*)w; w += (size_t)Bdim * Hdim * 4;    // 1 MB
  float* wsScores = (float*)w; w += (size_t)Bdim * Sdim * 4;
  unsigned* wsSeen = (unsigned*)w; w += (size_t)Bdim * SEENW * 4;

  prep_kernel<<<256, 256, 0, stream>>>(last_memory, wsLast, W_w, wsW, U_w, wsU,
                                       wsScores, wsLm, wsSeen);
  scatter_kernel<<<100, 256, 0, stream>>>(item_seq, wsSeen);

  // lm = last_memory @ W_w^T   (512x512x512, split-K=4, atomic accumulate)
  gemm_bt<0><<<dim3(Hdim / BN, Bdim / BM, 4), 512, 0, stream>>>(
      wsLast, wsW, nullptr, Bdim, Hdim, Hdim, wsLm, nullptr, nullptr, nullptr);
  // scores += sum_k V[k]*tanh(am + lm)   (25600x512x512), 100 m x 4 n = 400 blocks
  gemm_bt<1><<<dim3((Bdim * Sdim / BM) * (Hdim / BN)), 512, 0, stream>>>(
      nullptr, wsU, all_memory, Bdim * Sdim, Hdim, Hdim, nullptr,
      wsLm, V_w, wsScores);
  softmax_ctx_kernel<<<Bdim, 256, 0, stream>>>(wsScores, mask, all_memory, last_memory, wsFeat);
  // out^T = E_w @ feat^T  (20000x512x1024), 79 m-panels x 4 n-tiles = 316 blocks
  gemm_logits<<<dim3(((Ndim + BM - 1) / BM) * (Bdim / BN)), 512, 0, stream>>>(
      E_w, wsFeat, out, wsSeen);
}

// Round 12
// 125.435 us; speedup vs baseline: 1.3986x; 1.3986x over previous
//
#include <hip/hip_runtime.h>
#include <hip/hip_bf16.h>

#define Bdim 512
#define Sdim 50
#define Hdim 512
#define Ndim 20000
#define Kdim2 1024   // 2*H
#define SEENW 640    // u32 words per row for the seen-bitmask (20000 bits -> 625, pad 640)

typedef __bf16 bf16x8 __attribute__((ext_vector_type(8)));
typedef float f32x4 __attribute__((ext_vector_type(4)));
typedef unsigned short u16;

#define AS1 __attribute__((address_space(1)))
#define AS3 __attribute__((address_space(3)))

__device__ __forceinline__ u16 f2bf(float f) {
  unsigned u = __builtin_bit_cast(unsigned, f);
  u = (u + 0x7fffu + ((u >> 16) & 1u)) >> 16;   // RNE
  return (u16)u;
}
// HW packed fp32->bf16 (RNE), lo -> [15:0], hi -> [31:16]
__device__ __forceinline__ unsigned cvt_pk_bf16(float lo, float hi) {
  unsigned r;
  asm("v_cvt_pk_bf16_f32 %0, %1, %2" : "=v"(r) : "v"(lo), "v"(hi));
  return r;
}
__device__ __forceinline__ bf16x8 pack8(float4 lo, float4 hi) {
  union { unsigned u[4]; bf16x8 v; } r;
  r.u[0] = cvt_pk_bf16(lo.x, lo.y);
  r.u[1] = cvt_pk_bf16(lo.z, lo.w);
  r.u[2] = cvt_pk_bf16(hi.x, hi.y);
  r.u[3] = cvt_pk_bf16(hi.z, hi.w);
  return r.v;
}

// ---------------- prep: cast last_memory/W_w/U_w + zero scores/lm/seen ----------
__global__ __launch_bounds__(256) void prep_kernel(const float* __restrict__ a, u16* __restrict__ da,
                                                   const float* __restrict__ b, u16* __restrict__ db,
                                                   const float* __restrict__ c, u16* __restrict__ dc,
                                                   float* __restrict__ scores, float* __restrict__ lm,
                                                   unsigned* __restrict__ seen) {
  int i = blockIdx.x * blockDim.x + threadIdx.x;   // 65536 threads, one float4 each
  float4 v; ushort4 o;
  v = reinterpret_cast<const float4*>(a)[i];
  o.x = f2bf(v.x); o.y = f2bf(v.y); o.z = f2bf(v.z); o.w = f2bf(v.w);
  reinterpret_cast<ushort4*>(da)[i] = o;
  v = reinterpret_cast<const float4*>(b)[i];
  o.x = f2bf(v.x); o.y = f2bf(v.y); o.z = f2bf(v.z); o.w = f2bf(v.w);
  reinterpret_cast<ushort4*>(db)[i] = o;
  v = reinterpret_cast<const float4*>(c)[i];
  o.x = f2bf(v.x); o.y = f2bf(v.y); o.z = f2bf(v.z); o.w = f2bf(v.w);
  reinterpret_cast<ushort4*>(dc)[i] = o;
  int stride = gridDim.x * blockDim.x;
  for (int j = i; j < Bdim * Sdim; j += stride) scores[j] = 0.f;
  for (int j = i; j < Bdim * Hdim; j += stride) lm[j] = 0.f;
  for (int j = i; j < Bdim * SEENW; j += stride) seen[j] = 0u;
}

// ---------------- seen-item scatter ----------------
__global__ __launch_bounds__(256) void scatter_kernel(const int* __restrict__ iseq,
                                                      unsigned* __restrict__ seen) {
  int i = blockIdx.x * blockDim.x + threadIdx.x;
  if (i < Bdim * Sdim) {
    int b = i / Sdim;
    int it = iseq[i];
    if (it > 0) atomicOr(&seen[b * SEENW + (it >> 5)], 1u << (it & 31));
  }
}

// ---------------- softmax over S + context readout -> feat (bf16) ----------------
__global__ __launch_bounds__(256) void softmax_ctx_kernel(
    const float* __restrict__ scores, const unsigned char* __restrict__ mask,
    const float* __restrict__ amF, const float* __restrict__ last_memory,
    u16* __restrict__ feat) {
  int b = blockIdx.x;
  __shared__ float alpha[Sdim];
  int tid = threadIdx.x;
  if (tid < 64) {
    float s = -1e30f;
    if (tid < Sdim) {
      s = scores[b * Sdim + tid];
      if (mask[b * Sdim + tid]) s = -1e9f;   // mask is all-false in this problem
    }
    float m = s;
#pragma unroll
    for (int off = 32; off; off >>= 1) m = fmaxf(m, __shfl_xor(m, off));
    float e = (tid < Sdim) ? __expf(s - m) : 0.f;
    float sum = e;
#pragma unroll
    for (int off = 32; off; off >>= 1) sum += __shfl_xor(sum, off);
    if (tid < Sdim) alpha[tid] = e / sum;
  }
  __syncthreads();
  for (int h = tid; h < Hdim; h += 256) {
    const float* amp = amF + ((long)b * Sdim) * Hdim + h;
    float c = 0.f;
#pragma unroll 5
    for (int s = 0; s < Sdim; ++s) c += alpha[s] * amp[(long)s * Hdim];
    feat[b * Kdim2 + h] = f2bf(c);
    feat[b * Kdim2 + Hdim + h] = f2bf(last_memory[b * Hdim + h]);
  }
}

// ---------------- gemm_bt: 2-phase schedule for lm GEMM (EPI0) + scores GEMM (EPI1)
#define BM 256
#define BN 128
#define BK 32

template <int EPI>
__global__ __launch_bounds__(512, 4) void gemm_bt(
    const u16* __restrict__ A, const u16* __restrict__ Bmat,
    const float* __restrict__ Af,
    int M, int N, int K,
    float* __restrict__ out,
    const float* __restrict__ lm, const float* __restrict__ Vw,
    float* __restrict__ scores) {
  __shared__ bf16x8 Asl[2][BM * BK / 8];   // 2 x 1024 chunks of 16B = 32 KB
  __shared__ bf16x8 Bsl[2][BN * BK / 8];   // 2 x  512 chunks of 16B = 16 KB
  const int tid = threadIdx.x;
  const int lane = tid & 63;
  const int wid = tid >> 6;                 // 0..7
  const int wr = wid >> 1, wc = wid & 1;    // 4x2 wave grid, 64x64 per wave
  const int la = lane & 15, lb = lane >> 4;

  int bx, by, kt0, kt1;
  if constexpr (EPI == 0) {
    bx = blockIdx.x; by = blockIdx.y;
    int ktotal = K / BK; int kper = ktotal / gridDim.z;
    kt0 = blockIdx.z * kper; kt1 = kt0 + kper;
  } else {
    int nwg = gridDim.x, bid = blockIdx.x;
    int q = nwg >> 3, r = nwg & 7;
    int x = bid & 7, i = bid >> 3;
    int wgid = (x < r ? x * (q + 1) : r * (q + 1) + (x - r) * q) + i;
    by = wgid >> 2; bx = wgid & 3;          // 4 n-tiles of one A m-panel per XCD
    kt0 = 0; kt1 = K / BK;
  }
  const int m0 = by * BM;
  const int n0 = bx * BN;

  f32x4 acc[4][4];
  const f32x4 zero = {0.f, 0.f, 0.f, 0.f};
#pragma unroll
  for (int i = 0; i < 4; ++i)
#pragma unroll
    for (int j = 0; j < 4; ++j) acc[i][j] = zero;

  const int rw = tid >> 2;
  const int eA = (tid & 3) * 8;
  const int ch = tid & 3;
  int brB = n0 + rw; if (brB > N - 1) brB = N - 1;

  const u16 *gA0 = nullptr, *gA1 = nullptr, *gB = nullptr;
  const float *gAf0 = nullptr, *gAf1 = nullptr;
  if constexpr (EPI == 1) {
    gAf0 = Af + (long)(m0 + rw) * K + eA;
    gAf1 = Af + (long)(m0 + 128 + rw) * K + eA;
  } else {
    gA0 = A + (long)(m0 + rw) * K + eA;
    gA1 = A + (long)(m0 + 128 + rw) * K + eA;
  }
  gB = Bmat + (long)brB * K + eA;

  float4 ra0, ra1, ra2, ra3;   // EPI1: A fp32 staging regs

  auto STAGE_G = [&](int buf, int kt) {
    const int k0 = kt * BK;
    if constexpr (EPI != 1) {
      __builtin_amdgcn_global_load_lds((const AS1 void*)(gA0 + k0),
                                       (AS3 void*)(void*)&Asl[buf][wid * 64], 16, 0, 0);
      __builtin_amdgcn_global_load_lds((const AS1 void*)(gA1 + k0),
                                       (AS3 void*)(void*)&Asl[buf][512 + wid * 64], 16, 0, 0);
    }
    __builtin_amdgcn_global_load_lds((const AS1 void*)(gB + k0),
                                     (AS3 void*)(void*)&Bsl[buf][wid * 64], 16, 0, 0);
  };
  auto LOADR = [&](int kt) {
    const int k0 = kt * BK;
    if constexpr (EPI == 1) {
      ra0 = *reinterpret_cast<const float4*>(gAf0 + k0);
      ra1 = *reinterpret_cast<const float4*>(gAf0 + k0 + 4);
      ra2 = *reinterpret_cast<const float4*>(gAf1 + k0);
      ra3 = *reinterpret_cast<const float4*>(gAf1 + k0 + 4);
    }
  };
  auto WRITER = [&](int buf) {
    if constexpr (EPI == 1) {
      Asl[buf][rw * 4 + ch] = pack8(ra0, ra1);
      Asl[buf][(128 + rw) * 4 + ch] = pack8(ra2, ra3);
    }
  };

  STAGE_G(0, kt0);
  LOADR(kt0);
  WRITER(0);
  __syncthreads();
  int cur = 0;
  for (int kt = kt0; kt < kt1; ++kt) {
    const bool pf = (kt + 1 < kt1);
    if (pf) { STAGE_G(cur ^ 1, kt + 1); LOADR(kt + 1); }

    bf16x8 af[4], bfr[4];
#pragma unroll
    for (int mi = 0; mi < 4; ++mi)
      af[mi] = Asl[cur][(wr * 64 + mi * 16 + la) * 4 + lb];
#pragma unroll
    for (int ni = 0; ni < 4; ++ni)
      bfr[ni] = Bsl[cur][(wc * 64 + ni * 16 + la) * 4 + lb];
#pragma unroll
    for (int mi = 0; mi < 4; ++mi)
#pragma unroll
      for (int ni = 0; ni < 4; ++ni)
        acc[mi][ni] = __builtin_amdgcn_mfma_f32_16x16x32_bf16(af[mi], bfr[ni], acc[mi][ni], 0, 0, 0);

    if (pf) WRITER(cur ^ 1);
    __syncthreads();
    cur ^= 1;
  }

  // C/D layout (verified): col = lane&15, row = (lane>>4)*4 + reg
  if constexpr (EPI == 0) {
#pragma unroll
    for (int mi = 0; mi < 4; ++mi)
#pragma unroll
      for (int i = 0; i < 4; ++i) {
        int r = m0 + wr * 64 + mi * 16 + lb * 4 + i;
#pragma unroll
        for (int ni = 0; ni < 4; ++ni) {
          int c = n0 + wc * 64 + ni * 16 + la;
          atomicAdd(&out[(long)r * N + c], acc[mi][ni][i]);
        }
      }
  }
  if constexpr (EPI == 1) {
#pragma unroll
    for (int mi = 0; mi < 4; ++mi)
#pragma unroll
      for (int i = 0; i < 4; ++i) {
        int r = m0 + wr * 64 + mi * 16 + lb * 4 + i;
        int bidx = r / Sdim;
        float p = 0.f;
#pragma unroll
        for (int ni = 0; ni < 4; ++ni) {
          int c = n0 + wc * 64 + ni * 16 + la;
          float x = acc[mi][ni][i] + lm[bidx * Hdim + c];
          x = fminf(fmaxf(x, -9.f), 9.f);
          float e = __expf(2.f * x);
          p += Vw[c] * ((e - 1.f) / (e + 1.f));
        }
        p += __shfl_xor(p, 1);
        p += __shfl_xor(p, 2);
        p += __shfl_xor(p, 4);
        p += __shfl_xor(p, 8);
        if (la == 0) atomicAdd(&scores[r], p);
      }
  }
}

// ---------------- gemm_logits v6: r11 loop + LDS-transposed coalesced epilogue --
// Loop unchanged from r11 (out^T = E_w . feat^T, E-stream on the A/M side,
// fused cvt_pk, 4 n-tiles share each E-panel per XCD — EPI1's geometry).
// NEW epilogue: 4 passes (one per mi). Each pass transposes a 128(batch) x
// 64(item) f32 tile through LDS (pad 65 words -> conflict-free), applies
// sigmoid + seen-mask on read-back, and stores 64 B contiguous per thread.
// WRITE traffic: 105 MB scattered -> 40 MB coalesced; removes the L2 RMW
// pollution that contaminated r11's loop measurement.
__global__ __launch_bounds__(512, 2) void gemm_logits(
    const float* __restrict__ Ef, const u16* __restrict__ Feat,
    float* __restrict__ out, const unsigned* __restrict__ seen) {
  __shared__ __align__(16) char smem[49152];                 // 48 KB union
  bf16x8 (*Asl)[BM * BK / 8] = reinterpret_cast<bf16x8 (*)[BM * BK / 8]>(smem);          // 2 x 16 KB
  bf16x8 (*Bsl)[BN * BK / 8] = reinterpret_cast<bf16x8 (*)[BN * BK / 8]>(smem + 32768);  // 2 x 8 KB
  float (*T)[65] = reinterpret_cast<float (*)[65]>(smem);    // 128 x 65 f32 = 33.3 KB (epilogue)

  const int tid = threadIdx.x;
  const int lane = tid & 63;
  const int wid = tid >> 6;
  const int wr = wid >> 1, wc = wid & 1;    // 4m x 2n waves, 64x64 per wave
  const int la = lane & 15, lb = lane >> 4;
  const int NT = Kdim2 / BK;                // 32

  // bijective XCD swizzle (nwg=316): 4 n-tiles of one E m-panel consecutive
  int nwg = gridDim.x, bid = blockIdx.x;
  int q = nwg >> 3, r = nwg & 7;
  int x = bid & 7, i0 = bid >> 3;
  int wgid = (x < r ? x * (q + 1) : r * (q + 1) + (x - r) * q) + i0;
  const int by = wgid >> 2, bx = wgid & 3;
  const int m0 = by * BM;                   // E-row (item) panel
  const int n0 = bx * BN;                   // feat-row (batch) tile

  f32x4 acc[4][4];
  const f32x4 zero = {0.f, 0.f, 0.f, 0.f};
#pragma unroll
  for (int i = 0; i < 4; ++i)
#pragma unroll
    for (int j = 0; j < 4; ++j) acc[i][j] = zero;

  const int rw = tid >> 2;
  const int eA = (tid & 3) * 8;
  const int ch = tid & 3;

  long ar0 = m0 + rw;        if (ar0 > Ndim - 1) ar0 = Ndim - 1;   // clamp E rows
  long ar1 = m0 + 128 + rw;  if (ar1 > Ndim - 1) ar1 = Ndim - 1;
  const float* gAf0 = Ef + ar0 * Kdim2 + eA;
  const float* gAf1 = Ef + ar1 * Kdim2 + eA;
  const u16* gB = Feat + (long)(n0 + rw) * Kdim2 + eA;   // n0+rw <= 511 always

  float4 ra0, ra1, ra2, ra3;

  auto STAGE_G = [&](int buf, int kt) {     // feat -> LDS (async, L2-hot)
    const int k0 = kt * BK;
    __builtin_amdgcn_global_load_lds((const AS1 void*)(gB + k0),
                                     (AS3 void*)(void*)&Bsl[buf][wid * 64], 16, 0, 0);
  };
  auto LOADR = [&](int kt) {                // E_w fp32 stream -> regs
    const int k0 = kt * BK;
    ra0 = *reinterpret_cast<const float4*>(gAf0 + k0);
    ra1 = *reinterpret_cast<const float4*>(gAf0 + k0 + 4);
    ra2 = *reinterpret_cast<const float4*>(gAf1 + k0);
    ra3 = *reinterpret_cast<const float4*>(gAf1 + k0 + 4);
  };
  auto WRITER = [&](int buf) {              // cvt + ds_write after MFMA phase
    Asl[buf][rw * 4 + ch] = pack8(ra0, ra1);
    Asl[buf][(128 + rw) * 4 + ch] = pack8(ra2, ra3);
  };

  STAGE_G(0, 0);
  LOADR(0);
  WRITER(0);
  __syncthreads();
  int cur = 0;
  for (int kt = 0; kt < NT; ++kt) {
    const bool pf = (kt + 1 < NT);
    if (pf) { STAGE_G(cur ^ 1, kt + 1); LOADR(kt + 1); }

    bf16x8 af[4], bfr[4];
#pragma unroll
    for (int mi = 0; mi < 4; ++mi)
      af[mi] = Asl[cur][(wr * 64 + mi * 16 + la) * 4 + lb];
#pragma unroll
    for (int ni = 0; ni < 4; ++ni)
      bfr[ni] = Bsl[cur][(wc * 64 + ni * 16 + la) * 4 + lb];
#pragma unroll
    for (int mi = 0; mi < 4; ++mi)
#pragma unroll
      for (int ni = 0; ni < 4; ++ni)
        acc[mi][ni] = __builtin_amdgcn_mfma_f32_16x16x32_bf16(af[mi], bfr[ni], acc[mi][ni], 0, 0, 0);

    if (pf) WRITER(cur ^ 1);
    __syncthreads();
    cur ^= 1;
  }

  // ---- epilogue: 4 transpose passes through LDS, coalesced stores ----
  const int rr_l = tid >> 2;                 // store-back batch row 0..127
  const int sp = tid & 3;                    // 16-float span index
  const long rr_g = n0 + rr_l;               // global batch row
  float* orow = out + rr_g * Ndim;
  const unsigned* srow = seen + rr_g * SEENW;

#pragma unroll
  for (int mi = 0; mi < 4; ++mi) {
    __syncthreads();                         // previous pass reads done / loop LDS free
#pragma unroll
    for (int ni = 0; ni < 4; ++ni)
#pragma unroll
      for (int i = 0; i < 4; ++i)
        T[wc * 64 + ni * 16 + la][wr * 16 + lb * 4 + i] = acc[mi][ni][i];
    __syncthreads();
    const int c0 = m0 + sp * 64 + mi * 16;   // 16 consecutive item columns
    if (c0 < Ndim) {
      float vbuf[16];
#pragma unroll
      for (int j = 0; j < 16; ++j) {
        int c = c0 + j;
        float val = 0.f;
        if (c < Ndim) {
          unsigned wbits = srow[c >> 5];
          if (!((wbits >> (c & 31)) & 1u))
            val = 1.f / (1.f + __expf(-T[rr_l][sp * 16 + j]));
        }
        vbuf[j] = val;
      }
      if (c0 + 15 < Ndim) {
#pragma unroll
        for (int j = 0; j < 4; ++j)
          *reinterpret_cast<float4*>(orow + c0 + 4 * j) = *reinterpret_cast<float4*>(&vbuf[4 * j]);
      } else {
#pragma unroll
        for (int j = 0; j < 16; ++j)
          if (c0 + j < Ndim) orow[c0 + j] = vbuf[j];
      }
    }
  }
}

// ---------------- launcher ----------------
extern "C" void kernel_launch(void* const* d_in, const int* in_sizes, int n_in,
                              void* d_out, int out_size, void* d_ws, size_t ws_size,
                              hipStream_t stream) {
  (void)in_sizes; (void)n_in; (void)out_size; (void)ws_size;
  const float* all_memory  = (const float*)d_in[0];
  const float* last_memory = (const float*)d_in[1];
  const int*   item_seq    = (const int*)d_in[2];
  const unsigned char* mask = (const unsigned char*)d_in[3];
  const float* U_w = (const float*)d_in[4];
  const float* W_w = (const float*)d_in[5];
  const float* V_w = (const float*)d_in[6];
  const float* E_w = (const float*)d_in[8];
  float* out = (float*)d_out;

  char* w = (char*)d_ws;
  u16* wsFeat = (u16*)w; w += (size_t)Bdim * Kdim2 * 2;         // 1 MB
  u16* wsLast = (u16*)w; w += (size_t)Hdim * Hdim * 2;          // 0.5 MB
  u16* wsW    = (u16*)w; w += (size_t)Hdim * Hdim * 2;
  u16* wsU    = (u16*)w; w += (size_t)Hdim * Hdim * 2;
  float* wsLm     = (float*)w; w += (size_t)Bdim * Hdim * 4;    // 1 MB
  float* wsScores = (float*)w; w += (size_t)Bdim * Sdim * 4;
  unsigned* wsSeen = (unsigned*)w; w += (size_t)Bdim * SEENW * 4;

  prep_kernel<<<256, 256, 0, stream>>>(last_memory, wsLast, W_w, wsW, U_w, wsU,
                                       wsScores, wsLm, wsSeen);
  scatter_kernel<<<100, 256, 0, stream>>>(item_seq, wsSeen);

  // lm = last_memory @ W_w^T   (512x512x512, split-K=4, atomic accumulate)
  gemm_bt<0><<<dim3(Hdim / BN, Bdim / BM, 4), 512, 0, stream>>>(
      wsLast, wsW, nullptr, Bdim, Hdim, Hdim, wsLm, nullptr, nullptr, nullptr);
  // scores += sum_k V[k]*tanh(am + lm)   (25600x512x512), 100 m x 4 n = 400 blocks
  gemm_bt<1><<<dim3((Bdim * Sdim / BM) * (Hdim / BN)), 512, 0, stream>>>(
      nullptr, wsU, all_memory, Bdim * Sdim, Hdim, Hdim, nullptr,
      wsLm, V_w, wsScores);
  softmax_ctx_kernel<<<Bdim, 256, 0, stream>>>(wsScores, mask, all_memory, last_memory, wsFeat);
  // out^T = E_w @ feat^T  (20000x512x1024), 79 m-panels x 4 n-tiles = 316 blocks
  gemm_logits<<<dim3(((Ndim + BM - 1) / BM) * (Bdim / BN)), 512, 0, stream>>>(
      E_w, wsFeat, out, wsSeen);
}